// Round 1
// baseline (2236.805 us; speedup 1.0000x reference)
//
#include <hip/hip_runtime.h>

#define B_  8
#define N_  2048
#define M_  16384
#define KNN 20
#define NEG 0.2f

__device__ __forceinline__ unsigned enc_f(float f) {
    unsigned u = __float_as_uint(f);
    return (u & 0x80000000u) ? ~u : (u | 0x80000000u);
}
__device__ __forceinline__ float dec_f(unsigned u) {
    return (u & 0x80000000u) ? __uint_as_float(u & 0x7FFFFFFFu) : __uint_as_float(~u);
}

// wd[o][c] = w[o][C+c] - w[o][c]   (w is O x 2C row-major)
__global__ void wdiff_kernel(const float* __restrict__ w, float* __restrict__ wd,
                             int OC, int C) {
    int i = blockIdx.x * 256 + threadIdx.x;
    if (i < OC) {
        int o = i / C, c = i - o * C;
        wd[i] = w[(2 * o + 1) * C + c] - w[2 * o * C + c];
    }
}

// xx[m] = ||x_m||^2 ; xt[b][c][n] = x[m][c]
template<int C>
__global__ void prep_kernel(const float* __restrict__ x, int lda,
                            float* __restrict__ xx, float* __restrict__ xt) {
    int m = blockIdx.x * 256 + threadIdx.x;
    if (m >= M_) return;
    int b = m >> 11, n = m & 2047;
    const float* row = x + (size_t)m * lda;
    float s = 0.f;
#pragma unroll 8
    for (int c = 0; c < C; ++c) {
        float v = row[c];
        s = fmaf(v, v, s);
        xt[((size_t)b * C + c) * N_ + n] = v;
    }
    xx[m] = s;
}

// One block = 8 query rows of one batch. Computes full 8x2048 distance tile in
// LDS, then per-wave iterative top-20 extraction (exact set, tie -> lowest idx).
#define RM 8
template<int C>
__global__ __launch_bounds__(256, 2) void dist_topk_kernel(
        const float* __restrict__ xt, const float* __restrict__ xx,
        int* __restrict__ idxout) {
    __shared__ float dist[RM][N_];     // 64 KB
    __shared__ float xi[RM][C < 4 ? 4 : C];
    __shared__ float xxi_s[RM];
    int blk = blockIdx.x;
    int b = blk >> 8;                  // N_/RM = 256 blocks per batch
    int i0 = (blk & 255) * RM;
    int tid = threadIdx.x;

    for (int t = tid; t < RM * C; t += 256) {
        int r = t / C, c = t - r * C;
        xi[r][c] = xt[((size_t)b * C + c) * N_ + (i0 + r)];
    }
    if (tid < RM) xxi_s[tid] = xx[b * N_ + i0 + tid];
    __syncthreads();

    float acc[RM][8];
#pragma unroll
    for (int r = 0; r < RM; ++r)
#pragma unroll
        for (int p = 0; p < 8; ++p) acc[r][p] = 0.f;

    const float* xtb = xt + (size_t)b * C * N_;
#pragma unroll 4
    for (int c = 0; c < C; ++c) {
        float xtv[8];
#pragma unroll
        for (int p = 0; p < 8; ++p) xtv[p] = xtb[c * N_ + tid + 256 * p];
#pragma unroll
        for (int r = 0; r < RM; ++r) {
            float a = xi[r][c];
#pragma unroll
            for (int p = 0; p < 8; ++p) acc[r][p] = fmaf(a, xtv[p], acc[r][p]);
        }
    }
    float xxj[8];
#pragma unroll
    for (int p = 0; p < 8; ++p) xxj[p] = xx[b * N_ + tid + 256 * p];
#pragma unroll
    for (int r = 0; r < RM; ++r)
#pragma unroll
        for (int p = 0; p < 8; ++p)
            dist[r][tid + 256 * p] = xxi_s[r] + xxj[p] - 2.f * acc[r][p];
    __syncthreads();

    int wave = tid >> 6, lane = tid & 63;
    for (int rr = 0; rr < 2; ++rr) {
        int r = wave + rr * 4;
        float mv = 1e30f; int mi = 0;
        for (int q = 0; q < 32; ++q) {
            int j = lane + 64 * q;
            float v = dist[r][j];
            if (v < mv) { mv = v; mi = j; }
        }
        for (int it = 0; it < KNN; ++it) {
            float gv = mv; int gi = mi;
#pragma unroll
            for (int off = 32; off >= 1; off >>= 1) {
                float ov = __shfl_xor(gv, off);
                int   oi = __shfl_xor(gi, off);
                if (ov < gv || (ov == gv && oi < gi)) { gv = ov; gi = oi; }
            }
            if (lane == 0) idxout[(b * N_ + i0 + r) * KNN + it] = gi;
            if (lane == (gi & 63)) {      // owner re-derives its local min
                dist[r][gi] = 1e30f;
                mv = 1e30f; mi = 0;
                for (int q = 0; q < 32; ++q) {
                    int j = lane + 64 * q;
                    float v = dist[r][j];
                    if (v < mv) { mv = v; mi = j; }
                }
            }
        }
    }
}

// out[m][o] = f( sum_k A[m][k] * W[o][k] )  -- A: M x K (lda), W: O x K (ldw)
// MODE 0: raw store. MODE 1: lrelu((acc+addvec[b,o])*sc[o]+sh[o]) store.
// MODE 2: acc + sh[o] store. MODE 3: lrelu(acc*sc+sh), no store, atomicMax
//         per (batch,o) into gmax (uint-encoded float).
template<int MODE>
__global__ __launch_bounds__(256) void gemm_kernel(
        const float* __restrict__ A, int lda,
        const float* __restrict__ W, int ldw,
        float* __restrict__ out, int ldo,
        const float* __restrict__ sc, const float* __restrict__ sh,
        const float* __restrict__ addvec, unsigned* __restrict__ gmax,
        int K, int O) {
    __shared__ float As[16][68];
    __shared__ float Ws[16][68];
    int tid = threadIdx.x;
    int tx = tid & 15, ty = tid >> 4;
    int o0 = blockIdx.x * 64, m0 = blockIdx.y * 64;
    int lm = tid >> 2, lk = (tid & 3) << 2;
    float acc[4][4] = {};

    for (int k0 = 0; k0 < K; k0 += 16) {
#pragma unroll
        for (int e = 0; e < 4; ++e) {
            int k = k0 + lk + e;
            As[lk + e][lm] = (k < K) ? A[(size_t)(m0 + lm) * lda + k] : 0.f;
            int o = o0 + lm;
            Ws[lk + e][lm] = (k < K && o < O) ? W[(size_t)o * ldw + k] : 0.f;
        }
        __syncthreads();
#pragma unroll
        for (int kk = 0; kk < 16; ++kk) {
            float4 av = *(const float4*)&As[kk][ty << 2];
            float4 wv = *(const float4*)&Ws[kk][tx << 2];
            float a[4] = {av.x, av.y, av.z, av.w};
            float w[4] = {wv.x, wv.y, wv.z, wv.w};
#pragma unroll
            for (int i = 0; i < 4; ++i)
#pragma unroll
                for (int j = 0; j < 4; ++j)
                    acc[i][j] = fmaf(a[i], w[j], acc[i][j]);
        }
        __syncthreads();
    }

    int b = m0 >> 11;   // 64-row tile never crosses a batch (2048 % 64 == 0)
    if (MODE == 3) {
        float cmax[4];
#pragma unroll
        for (int j = 0; j < 4; ++j) cmax[j] = -1e30f;
#pragma unroll
        for (int i = 0; i < 4; ++i)
#pragma unroll
            for (int j = 0; j < 4; ++j) {
                int o = o0 + (tx << 2) + j;
                float v = fmaf(acc[i][j], sc[o], sh[o]);
                v = (v >= 0.f) ? v : NEG * v;
                cmax[j] = fmaxf(cmax[j], v);
            }
        __syncthreads();
        float* red = &As[0][0];
#pragma unroll
        for (int j = 0; j < 4; ++j) red[ty * 64 + (tx << 2) + j] = cmax[j];
        __syncthreads();
        if (ty == 0) {
#pragma unroll
            for (int j = 0; j < 4; ++j) {
                int o = o0 + (tx << 2) + j;
                float mval = -1e30f;
                for (int yy = 0; yy < 16; ++yy)
                    mval = fmaxf(mval, red[yy * 64 + (tx << 2) + j]);
                atomicMax(&gmax[b * 1024 + o], enc_f(mval));
            }
        }
        return;
    }
#pragma unroll
    for (int i = 0; i < 4; ++i) {
        int m = m0 + (ty << 2) + i;
#pragma unroll
        for (int j = 0; j < 4; ++j) {
            int o = o0 + (tx << 2) + j;
            if (o < O) {
                float v = acc[i][j];
                if (MODE == 1) {
                    if (addvec) v += addvec[b * O + o];
                    v = fmaf(v, sc[o], sh[o]);
                    v = (v >= 0.f) ? v : NEG * v;
                } else if (MODE == 2) {
                    v += sh[o];
                }
                out[(size_t)m * ldo + o] = v;
            }
        }
    }
}

// out[m][o] = max_k lrelu((y[nbr_k][o] + z[m][o]) * sc[o] + sh[o])
__global__ void edge_max_kernel(const float* __restrict__ y, const float* __restrict__ z,
                                const int* __restrict__ idx,
                                const float* __restrict__ sc, const float* __restrict__ sh,
                                float* __restrict__ out, int ldo, int oshift) {
    int gtid = blockIdx.x * 256 + threadIdx.x;
    int O = 1 << oshift;
    int m = gtid >> oshift, o = gtid & (O - 1);
    float zo = z[(size_t)m * O + o];
    float s = sc[o], t = sh[o];
    const int* ip = idx + m * KNN;
    int bbase = (m >> 11) << 11;
    float mv = -1e30f;
#pragma unroll
    for (int kk = 0; kk < KNN; ++kk) {
        int j = ip[kk];
        float v = fmaf(y[(size_t)(bbase + j) * O + o] + zo, s, t);
        v = (v >= 0.f) ? v : NEG * v;
        mv = fmaxf(mv, v);
    }
    out[(size_t)m * ldo + o] = mv;
}

__global__ void init_gmax_kernel(unsigned* __restrict__ g) {
    int i = blockIdx.x * 256 + threadIdx.x;
    if (i < B_ * 1024) g[i] = enc_f(-1e30f);
}
__global__ void decode_gmax_kernel(const unsigned* __restrict__ g, float* __restrict__ glob) {
    int i = blockIdx.x * 256 + threadIdx.x;
    if (i < B_ * 1024) glob[i] = dec_f(g[i]);
}

// corr[b][o] = sum_c glob[b][c] * h1w[o][512+c]   (one wave per (b,o))
__global__ void corr_kernel(const float* __restrict__ glob, const float* __restrict__ h1w,
                            float* __restrict__ corr) {
    int wid = (blockIdx.x * 256 + threadIdx.x) >> 6;
    int lane = threadIdx.x & 63;
    int b = wid >> 8, o = wid & 255;
    const float* g = glob + b * 1024;
    const float* w = h1w + (size_t)o * 1536 + 512;
    float s = 0.f;
    for (int c = lane; c < 1024; c += 64) s = fmaf(g[c], w[c], s);
#pragma unroll
    for (int off = 32; off >= 1; off >>= 1) s += __shfl_xor(s, off);
    if (lane == 0) corr[b * 256 + o] = s;
}

extern "C" void kernel_launch(void* const* d_in, const int* in_sizes, int n_in,
                              void* d_out, int out_size, void* d_ws, size_t ws_size,
                              hipStream_t stream) {
    const float* xyz    = (const float*)d_in[0];
    const float* ec1_w  = (const float*)d_in[1];
    const float* ec1_s  = (const float*)d_in[2];
    const float* ec1_t  = (const float*)d_in[3];
    const float* ec2_w  = (const float*)d_in[4];
    const float* ec2_s  = (const float*)d_in[5];
    const float* ec2_t  = (const float*)d_in[6];
    const float* ec3_w  = (const float*)d_in[7];
    const float* ec3_s  = (const float*)d_in[8];
    const float* ec3_t  = (const float*)d_in[9];
    const float* ec4_w  = (const float*)d_in[10];
    const float* ec4_s  = (const float*)d_in[11];
    const float* ec4_t  = (const float*)d_in[12];
    const float* fuse_w = (const float*)d_in[13];
    const float* fuse_s = (const float*)d_in[14];
    const float* fuse_t = (const float*)d_in[15];
    const float* emb_w  = (const float*)d_in[16];
    const float* emb_s  = (const float*)d_in[17];
    const float* emb_t  = (const float*)d_in[18];
    const float* h1_w   = (const float*)d_in[19];
    const float* h1_s   = (const float*)d_in[20];
    const float* h1_t   = (const float*)d_in[21];
    const float* h2_w   = (const float*)d_in[22];
    const float* h2_s   = (const float*)d_in[23];
    const float* h2_t   = (const float*)d_in[24];
    const float* h3_w   = (const float*)d_in[25];
    const float* h3_b   = (const float*)d_in[26];
    float* out = (float*)d_out;

    float* ws = (float*)d_ws;
    size_t off = 0;
    float* xcat = ws + off; off += (size_t)M_ * 512;
    float* xloc = ws + off; off += (size_t)M_ * 512;
    float* ybuf = ws + off; off += (size_t)M_ * 256;
    float* zbuf = ws + off; off += (size_t)M_ * 256;
    float* xt   = ws + off; off += (size_t)B_ * 128 * N_;
    float* xx   = ws + off; off += M_;
    int*   idx  = (int*)(ws + off); off += (size_t)M_ * KNN;
    float* wd1  = ws + off; off += 64 * 3;
    float* wd2  = ws + off; off += 64 * 64;
    float* wd3  = ws + off; off += 128 * 64;
    float* wd4  = ws + off; off += 256 * 128;
    unsigned* gmax = (unsigned*)(ws + off); off += B_ * 1024;
    float* glob = ws + off; off += B_ * 1024;
    float* corr = ws + off; off += B_ * 256;
    float* h1o  = ybuf;   // reuse after edge convs done
    float* h2o  = zbuf;

    // precompute W2-W1 for all 4 edge-conv layers
    wdiff_kernel<<<(64 * 3 + 255) / 256, 256, 0, stream>>>(ec1_w, wd1, 64 * 3, 3);
    wdiff_kernel<<<(64 * 64 + 255) / 256, 256, 0, stream>>>(ec2_w, wd2, 64 * 64, 64);
    wdiff_kernel<<<(128 * 64 + 255) / 256, 256, 0, stream>>>(ec3_w, wd3, 128 * 64, 64);
    wdiff_kernel<<<(256 * 128 + 255) / 256, 256, 0, stream>>>(ec4_w, wd4, 256 * 128, 128);

    // ---- EdgeConv 1: xyz (C=3) -> xcat[:, 0:64]
    prep_kernel<3><<<M_ / 256, 256, 0, stream>>>(xyz, 3, xx, xt);
    dist_topk_kernel<3><<<M_ / RM, 256, 0, stream>>>(xt, xx, idx);
    gemm_kernel<0><<<dim3(1, M_ / 64), 256, 0, stream>>>(xyz, 3, ec1_w, 6, ybuf, 64, nullptr, nullptr, nullptr, nullptr, 3, 64);
    gemm_kernel<0><<<dim3(1, M_ / 64), 256, 0, stream>>>(xyz, 3, wd1, 3, zbuf, 64, nullptr, nullptr, nullptr, nullptr, 3, 64);
    edge_max_kernel<<<(M_ * 64) / 256, 256, 0, stream>>>(ybuf, zbuf, idx, ec1_s, ec1_t, xcat + 0, 512, 6);

    // ---- EdgeConv 2: x1 (C=64) -> xcat[:, 64:128]
    prep_kernel<64><<<M_ / 256, 256, 0, stream>>>(xcat + 0, 512, xx, xt);
    dist_topk_kernel<64><<<M_ / RM, 256, 0, stream>>>(xt, xx, idx);
    gemm_kernel<0><<<dim3(1, M_ / 64), 256, 0, stream>>>(xcat + 0, 512, ec2_w, 128, ybuf, 64, nullptr, nullptr, nullptr, nullptr, 64, 64);
    gemm_kernel<0><<<dim3(1, M_ / 64), 256, 0, stream>>>(xcat + 0, 512, wd2, 64, zbuf, 64, nullptr, nullptr, nullptr, nullptr, 64, 64);
    edge_max_kernel<<<(M_ * 64) / 256, 256, 0, stream>>>(ybuf, zbuf, idx, ec2_s, ec2_t, xcat + 64, 512, 6);

    // ---- EdgeConv 3: x2 (C=64) -> xcat[:, 128:256]
    prep_kernel<64><<<M_ / 256, 256, 0, stream>>>(xcat + 64, 512, xx, xt);
    dist_topk_kernel<64><<<M_ / RM, 256, 0, stream>>>(xt, xx, idx);
    gemm_kernel<0><<<dim3(2, M_ / 64), 256, 0, stream>>>(xcat + 64, 512, ec3_w, 128, ybuf, 128, nullptr, nullptr, nullptr, nullptr, 64, 128);
    gemm_kernel<0><<<dim3(2, M_ / 64), 256, 0, stream>>>(xcat + 64, 512, wd3, 64, zbuf, 128, nullptr, nullptr, nullptr, nullptr, 64, 128);
    edge_max_kernel<<<(M_ * 128) / 256, 256, 0, stream>>>(ybuf, zbuf, idx, ec3_s, ec3_t, xcat + 128, 512, 7);

    // ---- EdgeConv 4: x3 (C=128) -> xcat[:, 256:512]
    prep_kernel<128><<<M_ / 256, 256, 0, stream>>>(xcat + 128, 512, xx, xt);
    dist_topk_kernel<128><<<M_ / RM, 256, 0, stream>>>(xt, xx, idx);
    gemm_kernel<0><<<dim3(4, M_ / 64), 256, 0, stream>>>(xcat + 128, 512, ec4_w, 256, ybuf, 256, nullptr, nullptr, nullptr, nullptr, 128, 256);
    gemm_kernel<0><<<dim3(4, M_ / 64), 256, 0, stream>>>(xcat + 128, 512, wd4, 128, zbuf, 256, nullptr, nullptr, nullptr, nullptr, 128, 256);
    edge_max_kernel<<<(M_ * 256) / 256, 256, 0, stream>>>(ybuf, zbuf, idx, ec4_s, ec4_t, xcat + 256, 512, 8);

    // ---- fuse: xcat(512) -> x_local(512), lrelu
    gemm_kernel<1><<<dim3(8, M_ / 64), 256, 0, stream>>>(xcat, 512, fuse_w, 512, xloc, 512, fuse_s, fuse_t, nullptr, nullptr, 512, 512);

    // ---- emb: x_local -> (max over N) glob, never materialized
    init_gmax_kernel<<<32, 256, 0, stream>>>(gmax);
    gemm_kernel<3><<<dim3(16, M_ / 64), 256, 0, stream>>>(xloc, 512, emb_w, 512, nullptr, 0, emb_s, emb_t, nullptr, gmax, 512, 1024);
    decode_gmax_kernel<<<32, 256, 0, stream>>>(gmax, glob);
    corr_kernel<<<512, 256, 0, stream>>>(glob, h1_w, corr);

    // ---- h1: [x_local | glob] (1536) -> 256 ; glob part folded in via corr
    gemm_kernel<1><<<dim3(4, M_ / 64), 256, 0, stream>>>(xloc, 512, h1_w, 1536, h1o, 256, h1_s, h1_t, corr, nullptr, 512, 256);
    // ---- h2: 256 -> 256
    gemm_kernel<1><<<dim3(4, M_ / 64), 256, 0, stream>>>(h1o, 256, h2_w, 256, h2o, 256, h2_s, h2_t, nullptr, nullptr, 256, 256);
    // ---- h3: 256 -> 13 (+bias)
    gemm_kernel<2><<<dim3(1, M_ / 64), 256, 0, stream>>>(h2o, 256, h3_w, 256, out, 13, nullptr, h3_b, nullptr, nullptr, 256, 13);
}

// Round 2
// 1642.060 us; speedup vs baseline: 1.3622x; 1.3622x over previous
//
#include <hip/hip_runtime.h>

#define B_  8
#define N_  2048
#define M_  16384
#define KNN 20
#define NEG 0.2f

__device__ __forceinline__ unsigned enc_f(float f) {
    unsigned u = __float_as_uint(f);
    return (u & 0x80000000u) ? ~u : (u | 0x80000000u);
}
__device__ __forceinline__ float dec_f(unsigned u) {
    return (u & 0x80000000u) ? __uint_as_float(u & 0x7FFFFFFFu) : __uint_as_float(~u);
}

// Build stacked edge-conv weight: ws rows [0,O) = W1 (first C cols of w),
// rows [O,2O) = W2-W1. Zero-padded to Kp columns.
__global__ void wstack_kernel(const float* __restrict__ w, float* __restrict__ ws,
                              int O, int C, int Kp) {
    int i = blockIdx.x * 256 + threadIdx.x;
    if (i >= 2 * O * Kp) return;
    int row = i / Kp, k = i - row * Kp;
    float v = 0.f;
    if (k < C) {
        int o = (row < O) ? row : row - O;
        float w1 = w[(size_t)o * 2 * C + k];
        v = (row < O) ? w1 : (w[(size_t)o * 2 * C + C + k] - w1);
    }
    ws[i] = v;
}

// xx[m] = ||x_m||^2 ; xt[b][c][n] = x[m][c]
template<int C>
__global__ void prep_kernel(const float* __restrict__ x, int lda,
                            float* __restrict__ xx, float* __restrict__ xt) {
    int m = blockIdx.x * 256 + threadIdx.x;
    if (m >= M_) return;
    int b = m >> 11, n = m & 2047;
    const float* row = x + (size_t)m * lda;
    float s = 0.f;
#pragma unroll 8
    for (int c = 0; c < C; ++c) {
        float v = row[c];
        s = fmaf(v, v, s);
        xt[((size_t)b * C + c) * N_ + n] = v;
    }
    xx[m] = s;
}

// One block = 8 query rows of one batch. Full 8x2048 distance tile in LDS,
// then per-wave iterative top-20 extraction (exact set, tie -> lowest idx).
#define RM 8
template<int C>
__global__ __launch_bounds__(256, 2) void dist_topk_kernel(
        const float* __restrict__ xt, const float* __restrict__ xx,
        int* __restrict__ idxout) {
    __shared__ float dist[RM][N_];     // 64 KB
    __shared__ float xi[RM][C < 4 ? 4 : C];
    __shared__ float xxi_s[RM];
    int blk = blockIdx.x;
    int b = blk >> 8;
    int i0 = (blk & 255) * RM;
    int tid = threadIdx.x;

    for (int t = tid; t < RM * C; t += 256) {
        int r = t / C, c = t - r * C;
        xi[r][c] = xt[((size_t)b * C + c) * N_ + (i0 + r)];
    }
    if (tid < RM) xxi_s[tid] = xx[b * N_ + i0 + tid];
    __syncthreads();

    float acc[RM][8];
#pragma unroll
    for (int r = 0; r < RM; ++r)
#pragma unroll
        for (int p = 0; p < 8; ++p) acc[r][p] = 0.f;

    const float* xtb = xt + (size_t)b * C * N_;
#pragma unroll 4
    for (int c = 0; c < C; ++c) {
        float xtv[8];
#pragma unroll
        for (int p = 0; p < 8; ++p) xtv[p] = xtb[c * N_ + tid + 256 * p];
#pragma unroll
        for (int r = 0; r < RM; ++r) {
            float a = xi[r][c];
#pragma unroll
            for (int p = 0; p < 8; ++p) acc[r][p] = fmaf(a, xtv[p], acc[r][p]);
        }
    }
    float xxj[8];
#pragma unroll
    for (int p = 0; p < 8; ++p) xxj[p] = xx[b * N_ + tid + 256 * p];
#pragma unroll
    for (int r = 0; r < RM; ++r)
#pragma unroll
        for (int p = 0; p < 8; ++p)
            dist[r][tid + 256 * p] = xxi_s[r] + xxj[p] - 2.f * acc[r][p];
    __syncthreads();

    int wave = tid >> 6, lane = tid & 63;
    for (int rr = 0; rr < 2; ++rr) {
        int r = wave + rr * 4;
        float mv = 1e30f; int mi = 0;
        for (int q = 0; q < 32; ++q) {
            int j = lane + 64 * q;
            float v = dist[r][j];
            if (v < mv) { mv = v; mi = j; }
        }
        for (int it = 0; it < KNN; ++it) {
            float gv = mv; int gi = mi;
#pragma unroll
            for (int off = 32; off >= 1; off >>= 1) {
                float ov = __shfl_xor(gv, off);
                int   oi = __shfl_xor(gi, off);
                if (ov < gv || (ov == gv && oi < gi)) { gv = ov; gi = oi; }
            }
            if (lane == 0) idxout[(b * N_ + i0 + r) * KNN + it] = gi;
            if (lane == (gi & 63)) {
                dist[r][gi] = 1e30f;
                mv = 1e30f; mi = 0;
                for (int q = 0; q < 32; ++q) {
                    int j = lane + 64 * q;
                    float v = dist[r][j];
                    if (v < mv) { mv = v; mi = j; }
                }
            }
        }
    }
}

// C = A * W^T with A: M x K (lda), W: O x K (ldw). Block tile 128 x TN,
// 256 threads, per-thread 8 x (TN/16). BK = 16.
// MODE 0: raw store. MODE 1: lrelu((acc+addvec[b,o])*sc+sh). MODE 2: acc+sh.
// MODE 3: lrelu(acc*sc+sh) -> per-(b,o) atomicMax into gmax, no store.
// VEC=false: scalar guarded A staging (for K=3 / unaligned lda).
template<int TN, int MODE, bool VEC>
__global__ __launch_bounds__(256, 3) void gemm_kernel(
        const float* __restrict__ A, int lda,
        const float* __restrict__ W, int ldw,
        float* __restrict__ out, int ldo,
        const float* __restrict__ sc, const float* __restrict__ sh,
        const float* __restrict__ addvec, unsigned* __restrict__ gmax,
        int K, int O) {
    constexpr int TM = 128;
    constexpr int JN = TN / 16;          // cols per thread (8 or 4)
    __shared__ float As[16][TM];
    __shared__ float Bs[16][TN];
    int tid = threadIdx.x;
    int tx = tid & 15, ty = tid >> 4;
    int o0 = blockIdx.x * TN, m0 = blockIdx.y * TM;
    float acc[8][JN] = {};

    for (int k0 = 0; k0 < K; k0 += 16) {
        if constexpr (VEC) {
#pragma unroll
            for (int s = 0; s < 2; ++s) {          // A: 512 float4 slots
                int t = tid + s * 256;
                int row = t >> 2, c4 = (t & 3) << 2;
                float4 v = *(const float4*)&A[(size_t)(m0 + row) * lda + k0 + c4];
                As[c4 + 0][row] = v.x; As[c4 + 1][row] = v.y;
                As[c4 + 2][row] = v.z; As[c4 + 3][row] = v.w;
            }
#pragma unroll
            for (int s = 0; s < TN / 64; ++s) {    // B: TN*4 float4 slots
                int t = tid + s * 256;
                int row = t >> 2, c4 = (t & 3) << 2;
                int o = o0 + row;
                float4 v = make_float4(0.f, 0.f, 0.f, 0.f);
                if (o < O) v = *(const float4*)&W[(size_t)o * ldw + k0 + c4];
                Bs[c4 + 0][row] = v.x; Bs[c4 + 1][row] = v.y;
                Bs[c4 + 2][row] = v.z; Bs[c4 + 3][row] = v.w;
            }
        } else {
            for (int t = tid; t < TM * 16; t += 256) {
                int row = t >> 4, k = t & 15;
                As[k][row] = (k0 + k < K) ? A[(size_t)(m0 + row) * lda + k0 + k] : 0.f;
            }
            for (int t = tid; t < TN * 16; t += 256) {
                int row = t >> 4, k = t & 15;
                Bs[k][row] = W[(size_t)(o0 + row) * ldw + k0 + k];  // zero-padded wstack
            }
        }
        __syncthreads();
#pragma unroll
        for (int kk = 0; kk < 16; ++kk) {
            float a[8], b[JN];
            *(float4*)&a[0] = *(const float4*)&As[kk][ty * 8];
            *(float4*)&a[4] = *(const float4*)&As[kk][ty * 8 + 4];
            *(float4*)&b[0] = *(const float4*)&Bs[kk][tx * JN];
            if (JN == 8) *(float4*)&b[4] = *(const float4*)&Bs[kk][tx * JN + 4];
#pragma unroll
            for (int i = 0; i < 8; ++i)
#pragma unroll
                for (int j = 0; j < JN; ++j)
                    acc[i][j] = fmaf(a[i], b[j], acc[i][j]);
        }
        __syncthreads();
    }

    int b = m0 >> 11;   // 128-row tile never crosses a batch
    if constexpr (MODE == 3) {
        float cmax[JN];
#pragma unroll
        for (int j = 0; j < JN; ++j) cmax[j] = -1e30f;
#pragma unroll
        for (int i = 0; i < 8; ++i)
#pragma unroll
            for (int j = 0; j < JN; ++j) {
                int o = o0 + tx * JN + j;
                float v = fmaf(acc[i][j], sc[o], sh[o]);
                v = (v >= 0.f) ? v : NEG * v;
                cmax[j] = fmaxf(cmax[j], v);
            }
        __syncthreads();
#pragma unroll
        for (int j = 0; j < JN; ++j) Bs[ty][tx * JN + j] = cmax[j];
        __syncthreads();
        if (ty == 0) {
#pragma unroll
            for (int j = 0; j < JN; ++j) {
                int o = o0 + tx * JN + j;
                float mval = -1e30f;
                for (int yy = 0; yy < 16; ++yy)
                    mval = fmaxf(mval, Bs[yy][tx * JN + j]);
                atomicMax(&gmax[b * 1024 + o], enc_f(mval));
            }
        }
        return;
    }

    bool fullstore = (o0 + TN <= O) && ((ldo & 3) == 0);
#pragma unroll
    for (int i = 0; i < 8; ++i) {
        int m = m0 + ty * 8 + i;
        float vals[JN];
#pragma unroll
        for (int j = 0; j < JN; ++j) {
            int o = o0 + tx * JN + j;
            float v = acc[i][j];
            if (MODE == 1) {
                if (addvec) v += addvec[b * O + o];
                v = fmaf(v, sc[o], sh[o]);
                v = (v >= 0.f) ? v : NEG * v;
            } else if (MODE == 2) {
                v += sh[o];
            }
            vals[j] = v;
        }
        if (fullstore) {
#pragma unroll
            for (int j0 = 0; j0 < JN; j0 += 4)
                *(float4*)&out[(size_t)m * ldo + o0 + tx * JN + j0] = *(float4*)&vals[j0];
        } else {
#pragma unroll
            for (int j = 0; j < JN; ++j) {
                int o = o0 + tx * JN + j;
                if (o < O) out[(size_t)m * ldo + o] = vals[j];
            }
        }
    }
}

// out[m][o..o+3] = max_k lrelu((y[nbr_k] + z[m]) * sc + sh), y/z packed in yz:
// y = yz[.][0:O), z = yz[.][O:2O). oshift = log2(O).
__global__ void edge_max_kernel(const float* __restrict__ yz, const int* __restrict__ idx,
                                const float* __restrict__ sc, const float* __restrict__ sh,
                                float* __restrict__ out, int ldo, int oshift) {
    int gid = blockIdx.x * 256 + threadIdx.x;
    int O = 1 << oshift;
    int m = gid >> (oshift - 2);
    int o = (gid & ((1 << (oshift - 2)) - 1)) << 2;
    int ldyz = 2 * O;
    float4 z = *(const float4*)&yz[(size_t)m * ldyz + O + o];
    float4 s4 = *(const float4*)&sc[o];
    float4 t4 = *(const float4*)&sh[o];
    const int* ip = idx + m * KNN;
    int bbase = m & ~(N_ - 1);
    float4 mv = make_float4(-1e30f, -1e30f, -1e30f, -1e30f);
#pragma unroll
    for (int kk = 0; kk < KNN; ++kk) {
        int j = ip[kk];
        float4 y = *(const float4*)&yz[(size_t)(bbase + j) * ldyz + o];
        float v;
        v = fmaf(y.x + z.x, s4.x, t4.x); v = (v >= 0.f) ? v : NEG * v; mv.x = fmaxf(mv.x, v);
        v = fmaf(y.y + z.y, s4.y, t4.y); v = (v >= 0.f) ? v : NEG * v; mv.y = fmaxf(mv.y, v);
        v = fmaf(y.z + z.z, s4.z, t4.z); v = (v >= 0.f) ? v : NEG * v; mv.z = fmaxf(mv.z, v);
        v = fmaf(y.w + z.w, s4.w, t4.w); v = (v >= 0.f) ? v : NEG * v; mv.w = fmaxf(mv.w, v);
    }
    *(float4*)&out[(size_t)m * ldo + o] = mv;
}

__global__ void init_gmax_kernel(unsigned* __restrict__ g) {
    int i = blockIdx.x * 256 + threadIdx.x;
    if (i < B_ * 1024) g[i] = enc_f(-1e30f);
}
__global__ void decode_gmax_kernel(const unsigned* __restrict__ g, float* __restrict__ glob) {
    int i = blockIdx.x * 256 + threadIdx.x;
    if (i < B_ * 1024) glob[i] = dec_f(g[i]);
}

// corr[b][o] = sum_c glob[b][c] * h1w[o][512+c]
__global__ void corr_kernel(const float* __restrict__ glob, const float* __restrict__ h1w,
                            float* __restrict__ corr) {
    int wid = (blockIdx.x * 256 + threadIdx.x) >> 6;
    int lane = threadIdx.x & 63;
    int b = wid >> 8, o = wid & 255;
    const float* g = glob + b * 1024;
    const float* w = h1w + (size_t)o * 1536 + 512;
    float s = 0.f;
    for (int c = lane; c < 1024; c += 64) s = fmaf(g[c], w[c], s);
#pragma unroll
    for (int off = 32; off >= 1; off >>= 1) s += __shfl_xor(s, off);
    if (lane == 0) corr[b * 256 + o] = s;
}

extern "C" void kernel_launch(void* const* d_in, const int* in_sizes, int n_in,
                              void* d_out, int out_size, void* d_ws, size_t ws_size,
                              hipStream_t stream) {
    const float* xyz    = (const float*)d_in[0];
    const float* ec1_w  = (const float*)d_in[1];
    const float* ec1_s  = (const float*)d_in[2];
    const float* ec1_t  = (const float*)d_in[3];
    const float* ec2_w  = (const float*)d_in[4];
    const float* ec2_s  = (const float*)d_in[5];
    const float* ec2_t  = (const float*)d_in[6];
    const float* ec3_w  = (const float*)d_in[7];
    const float* ec3_s  = (const float*)d_in[8];
    const float* ec3_t  = (const float*)d_in[9];
    const float* ec4_w  = (const float*)d_in[10];
    const float* ec4_s  = (const float*)d_in[11];
    const float* ec4_t  = (const float*)d_in[12];
    const float* fuse_w = (const float*)d_in[13];
    const float* fuse_s = (const float*)d_in[14];
    const float* fuse_t = (const float*)d_in[15];
    const float* emb_w  = (const float*)d_in[16];
    const float* emb_s  = (const float*)d_in[17];
    const float* emb_t  = (const float*)d_in[18];
    const float* h1_w   = (const float*)d_in[19];
    const float* h1_s   = (const float*)d_in[20];
    const float* h1_t   = (const float*)d_in[21];
    const float* h2_w   = (const float*)d_in[22];
    const float* h2_s   = (const float*)d_in[23];
    const float* h2_t   = (const float*)d_in[24];
    const float* h3_w   = (const float*)d_in[25];
    const float* h3_b   = (const float*)d_in[26];
    float* out = (float*)d_out;

    float* ws = (float*)d_ws;
    size_t off = 0;
    float* xcat = ws + off; off += (size_t)M_ * 512;
    float* xloc = ws + off; off += (size_t)M_ * 512;
    float* yz   = ws + off; off += (size_t)M_ * 512;
    float* xt   = ws + off; off += (size_t)B_ * 128 * N_;
    float* xx   = ws + off; off += M_;
    int*   idx  = (int*)(ws + off); off += (size_t)M_ * KNN;
    float* ws1  = ws + off; off += 2 * 64 * 16;
    float* ws2  = ws + off; off += 2 * 64 * 64;
    float* ws3  = ws + off; off += 2 * 128 * 64;
    float* ws4  = ws + off; off += 2 * 256 * 128;
    unsigned* gmax = (unsigned*)(ws + off); off += B_ * 1024;
    float* glob = ws + off; off += B_ * 1024;
    float* corr = ws + off; off += B_ * 256;
    float* h1o  = yz;                 // reuse after ec4's edge_max
    float* h2o  = yz + (size_t)M_ * 256;

    wstack_kernel<<<(2 * 64 * 16 + 255) / 256, 256, 0, stream>>>(ec1_w, ws1, 64, 3, 16);
    wstack_kernel<<<(2 * 64 * 64 + 255) / 256, 256, 0, stream>>>(ec2_w, ws2, 64, 64, 64);
    wstack_kernel<<<(2 * 128 * 64 + 255) / 256, 256, 0, stream>>>(ec3_w, ws3, 128, 64, 64);
    wstack_kernel<<<(2 * 256 * 128 + 255) / 256, 256, 0, stream>>>(ec4_w, ws4, 256, 128, 128);

    // ---- EdgeConv 1: xyz (C=3) -> xcat[:, 0:64]
    prep_kernel<3><<<M_ / 256, 256, 0, stream>>>(xyz, 3, xx, xt);
    dist_topk_kernel<3><<<M_ / RM, 256, 0, stream>>>(xt, xx, idx);
    gemm_kernel<128, 0, false><<<dim3(1, M_ / 128), 256, 0, stream>>>(xyz, 3, ws1, 16, yz, 128, nullptr, nullptr, nullptr, nullptr, 3, 128);
    edge_max_kernel<<<(M_ * 16) / 256, 256, 0, stream>>>(yz, idx, ec1_s, ec1_t, xcat + 0, 512, 6);

    // ---- EdgeConv 2: x1 (C=64) -> xcat[:, 64:128]
    prep_kernel<64><<<M_ / 256, 256, 0, stream>>>(xcat + 0, 512, xx, xt);
    dist_topk_kernel<64><<<M_ / RM, 256, 0, stream>>>(xt, xx, idx);
    gemm_kernel<64, 0, true><<<dim3(2, M_ / 128), 256, 0, stream>>>(xcat + 0, 512, ws2, 64, yz, 128, nullptr, nullptr, nullptr, nullptr, 64, 128);
    edge_max_kernel<<<(M_ * 16) / 256, 256, 0, stream>>>(yz, idx, ec2_s, ec2_t, xcat + 64, 512, 6);

    // ---- EdgeConv 3: x2 (C=64) -> xcat[:, 128:256]
    prep_kernel<64><<<M_ / 256, 256, 0, stream>>>(xcat + 64, 512, xx, xt);
    dist_topk_kernel<64><<<M_ / RM, 256, 0, stream>>>(xt, xx, idx);
    gemm_kernel<128, 0, true><<<dim3(2, M_ / 128), 256, 0, stream>>>(xcat + 64, 512, ws3, 64, yz, 256, nullptr, nullptr, nullptr, nullptr, 64, 256);
    edge_max_kernel<<<(M_ * 32) / 256, 256, 0, stream>>>(yz, idx, ec3_s, ec3_t, xcat + 128, 512, 7);

    // ---- EdgeConv 4: x3 (C=128) -> xcat[:, 256:512]
    prep_kernel<128><<<M_ / 256, 256, 0, stream>>>(xcat + 128, 512, xx, xt);
    dist_topk_kernel<128><<<M_ / RM, 256, 0, stream>>>(xt, xx, idx);
    gemm_kernel<128, 0, true><<<dim3(4, M_ / 128), 256, 0, stream>>>(xcat + 128, 512, ws4, 128, yz, 512, nullptr, nullptr, nullptr, nullptr, 128, 512);
    edge_max_kernel<<<(M_ * 64) / 256, 256, 0, stream>>>(yz, idx, ec4_s, ec4_t, xcat + 256, 512, 8);

    // ---- fuse: xcat(512) -> x_local(512), lrelu
    gemm_kernel<128, 1, true><<<dim3(4, M_ / 128), 256, 0, stream>>>(xcat, 512, fuse_w, 512, xloc, 512, fuse_s, fuse_t, nullptr, nullptr, 512, 512);

    // ---- emb: x_local -> (max over N) glob, never materialized
    init_gmax_kernel<<<32, 256, 0, stream>>>(gmax);
    gemm_kernel<128, 3, true><<<dim3(8, M_ / 128), 256, 0, stream>>>(xloc, 512, emb_w, 512, nullptr, 0, emb_s, emb_t, nullptr, gmax, 512, 1024);
    decode_gmax_kernel<<<32, 256, 0, stream>>>(gmax, glob);
    corr_kernel<<<512, 256, 0, stream>>>(glob, h1_w, corr);

    // ---- h1: [x_local | glob] (1536) -> 256 ; glob part folded in via corr
    gemm_kernel<128, 1, true><<<dim3(2, M_ / 128), 256, 0, stream>>>(xloc, 512, h1_w, 1536, h1o, 256, h1_s, h1_t, corr, nullptr, 512, 256);
    // ---- h2: 256 -> 256
    gemm_kernel<128, 1, true><<<dim3(2, M_ / 128), 256, 0, stream>>>(h1o, 256, h2_w, 256, h2o, 256, h2_s, h2_t, nullptr, nullptr, 256, 256);
    // ---- h3: 256 -> 13 (+bias)
    gemm_kernel<64, 2, true><<<dim3(1, M_ / 128), 256, 0, stream>>>(h2o, 256, h3_w, 256, out, 13, nullptr, h3_b, nullptr, nullptr, 256, 13);
}

// Round 3
// 1308.411 us; speedup vs baseline: 1.7096x; 1.2550x over previous
//
#include <hip/hip_runtime.h>

#define B_  8
#define N_  2048
#define M_  16384
#define KNN 20
#define NEG 0.2f
#define KEYMAX 0xFFFFFFFFFFFFFFFFull

__device__ __forceinline__ unsigned enc_f(float f) {
    unsigned u = __float_as_uint(f);
    return (u & 0x80000000u) ? ~u : (u | 0x80000000u);
}
__device__ __forceinline__ float dec_f(unsigned u) {
    return (u & 0x80000000u) ? __uint_as_float(u & 0x7FFFFFFFu) : __uint_as_float(~u);
}
__device__ __forceinline__ unsigned long long umin64(unsigned long long a, unsigned long long b) {
    return (b < a) ? b : a;
}

// Build stacked edge-conv weight: rows [0,O) = W1, rows [O,2O) = W2-W1, padded to Kp.
__global__ void wstack_kernel(const float* __restrict__ w, float* __restrict__ ws,
                              int O, int C, int Kp) {
    int i = blockIdx.x * 256 + threadIdx.x;
    if (i >= 2 * O * Kp) return;
    int row = i / Kp, k = i - row * Kp;
    float v = 0.f;
    if (k < C) {
        int o = (row < O) ? row : row - O;
        float w1 = w[(size_t)o * 2 * C + k];
        v = (row < O) ? w1 : (w[(size_t)o * 2 * C + C + k] - w1);
    }
    ws[i] = v;
}

// xx[m] = ||x_m||^2 ; xt[b][c][n] = x[m][c]
template<int C>
__global__ void prep_kernel(const float* __restrict__ x, int lda,
                            float* __restrict__ xx, float* __restrict__ xt) {
    int m = blockIdx.x * 256 + threadIdx.x;
    if (m >= M_) return;
    int b = m >> 11, n = m & 2047;
    const float* row = x + (size_t)m * lda;
    float s = 0.f;
#pragma unroll 8
    for (int c = 0; c < C; ++c) {
        float v = row[c];
        s = fmaf(v, v, s);
        xt[((size_t)b * C + c) * N_ + n] = v;
    }
    xx[m] = s;
}

// One block (512 thr) = 8 query rows. Distance tile in LDS; extraction: one
// wave per row, per-lane two-level min tree over u64 keys enc(d)<<11|j
// (exact set + tie -> lowest index, matching lax.top_k).
#define RM 8
template<int C>
__global__ __launch_bounds__(512, 4) void dist_topk_kernel(
        const float* __restrict__ xt, const float* __restrict__ xx,
        int* __restrict__ idxout) {
    __shared__ float dist[RM][N_];     // 64 KB
    __shared__ float xi[RM][C < 4 ? 4 : C];
    __shared__ float xxi_s[RM];
    int blk = blockIdx.x;
    int b = blk >> 8;
    int i0 = (blk & 255) * RM;
    int tid = threadIdx.x;

    for (int t = tid; t < RM * C; t += 512) {
        int r = t / C, c = t - r * C;
        xi[r][c] = xt[((size_t)b * C + c) * N_ + (i0 + r)];
    }
    if (tid < RM) xxi_s[tid] = xx[b * N_ + i0 + tid];
    __syncthreads();

    // ---- distance compute: thread -> 4 cols x 8 rows
    float acc[RM][4];
#pragma unroll
    for (int r = 0; r < RM; ++r)
#pragma unroll
        for (int p = 0; p < 4; ++p) acc[r][p] = 0.f;

    const float* xtb = xt + (size_t)b * C * N_;
#pragma unroll 4
    for (int c = 0; c < C; ++c) {
        float xtv[4];
#pragma unroll
        for (int p = 0; p < 4; ++p) xtv[p] = xtb[c * N_ + tid + 512 * p];
#pragma unroll
        for (int r = 0; r < RM; ++r) {
            float a = xi[r][c];
#pragma unroll
            for (int p = 0; p < 4; ++p) acc[r][p] = fmaf(a, xtv[p], acc[r][p]);
        }
    }
    float xxj[4];
#pragma unroll
    for (int p = 0; p < 4; ++p) xxj[p] = xx[b * N_ + tid + 512 * p];
#pragma unroll
    for (int r = 0; r < RM; ++r)
#pragma unroll
        for (int p = 0; p < 4; ++p)
            dist[r][tid + 512 * p] = xxi_s[r] + xxj[p] - 2.f * acc[r][p];
    __syncthreads();

    // ---- extraction: wave w -> row w
    int r = tid >> 6, lane = tid & 63;

    unsigned long long gm[8];
#pragma unroll
    for (int g = 0; g < 8; ++g) {
        unsigned long long m = KEYMAX;
#pragma unroll
        for (int e = 0; e < 4; ++e) {
            int j = lane + 64 * (g * 4 + e);
            unsigned long long kk = ((unsigned long long)enc_f(dist[r][j]) << 11) | (unsigned)j;
            m = umin64(m, kk);
        }
        gm[g] = m;
    }

    int* orow = idxout + (b * N_ + i0 + r) * KNN;
    for (int it = 0; it < KNN; ++it) {
        unsigned long long lmin = gm[0];
#pragma unroll
        for (int g = 1; g < 8; ++g) lmin = umin64(lmin, gm[g]);
#pragma unroll
        for (int off = 32; off >= 1; off >>= 1)
            lmin = umin64(lmin, (unsigned long long)__shfl_xor((unsigned long long)lmin, off));
        int j = (int)(lmin & 2047u);
        if (lane == 0) {
            orow[it] = j;
            dist[r][j] = 1e30f;          // invalidate for future pulls
        }
        __builtin_amdgcn_wave_barrier();  // keep write before the rebuild reads
        int sj = __builtin_amdgcn_readfirstlane(j);
        int qb = (sj >> 6) & ~3;          // group base q of extracted element
        unsigned long long nm = KEYMAX;
#pragma unroll
        for (int e = 0; e < 4; ++e) {
            int j2 = lane + 64 * (qb + e);
            unsigned long long kk = ((unsigned long long)enc_f(dist[r][j2]) << 11) | (unsigned)j2;
            if (j2 == sj) kk = KEYMAX;    // value-level invalidation this pull
            nm = umin64(nm, kk);
        }
        int gsel = sj >> 8;
#pragma unroll
        for (int gg = 0; gg < 8; ++gg)
            if (gg == gsel) gm[gg] = nm;
    }
}

// C = A * W^T. Block tile 128 x TN, 256 threads, per-thread 8 x (TN/16). BK=16.
// MODE 0: raw. MODE 1: lrelu((acc+addvec)*sc+sh). MODE 2: acc+sh.
// MODE 3: lrelu(acc*sc+sh) -> per-(b,o) atomicMax into gmax.
template<int TN, int MODE, bool VEC>
__global__ __launch_bounds__(256, 3) void gemm_kernel(
        const float* __restrict__ A, int lda,
        const float* __restrict__ W, int ldw,
        float* __restrict__ out, int ldo,
        const float* __restrict__ sc, const float* __restrict__ sh,
        const float* __restrict__ addvec, unsigned* __restrict__ gmax,
        int K, int O) {
    constexpr int TM = 128;
    constexpr int JN = TN / 16;
    __shared__ float As[16][TM];
    __shared__ float Bs[16][TN];
    int tid = threadIdx.x;
    int tx = tid & 15, ty = tid >> 4;
    int o0 = blockIdx.x * TN, m0 = blockIdx.y * TM;
    float acc[8][JN] = {};

    for (int k0 = 0; k0 < K; k0 += 16) {
        if constexpr (VEC) {
#pragma unroll
            for (int s = 0; s < 2; ++s) {
                int t = tid + s * 256;
                int row = t >> 2, c4 = (t & 3) << 2;
                float4 v = *(const float4*)&A[(size_t)(m0 + row) * lda + k0 + c4];
                As[c4 + 0][row] = v.x; As[c4 + 1][row] = v.y;
                As[c4 + 2][row] = v.z; As[c4 + 3][row] = v.w;
            }
#pragma unroll
            for (int s = 0; s < TN / 64; ++s) {
                int t = tid + s * 256;
                int row = t >> 2, c4 = (t & 3) << 2;
                int o = o0 + row;
                float4 v = make_float4(0.f, 0.f, 0.f, 0.f);
                if (o < O) v = *(const float4*)&W[(size_t)o * ldw + k0 + c4];
                Bs[c4 + 0][row] = v.x; Bs[c4 + 1][row] = v.y;
                Bs[c4 + 2][row] = v.z; Bs[c4 + 3][row] = v.w;
            }
        } else {
            for (int t = tid; t < TM * 16; t += 256) {
                int row = t >> 4, k = t & 15;
                As[k][row] = (k0 + k < K) ? A[(size_t)(m0 + row) * lda + k0 + k] : 0.f;
            }
            for (int t = tid; t < TN * 16; t += 256) {
                int row = t >> 4, k = t & 15;
                Bs[k][row] = W[(size_t)(o0 + row) * ldw + k0 + k];
            }
        }
        __syncthreads();
#pragma unroll
        for (int kk = 0; kk < 16; ++kk) {
            float a[8], bv[JN];
            *(float4*)&a[0] = *(const float4*)&As[kk][ty * 8];
            *(float4*)&a[4] = *(const float4*)&As[kk][ty * 8 + 4];
            *(float4*)&bv[0] = *(const float4*)&Bs[kk][tx * JN];
            if (JN == 8) *(float4*)&bv[4] = *(const float4*)&Bs[kk][tx * JN + 4];
#pragma unroll
            for (int i = 0; i < 8; ++i)
#pragma unroll
                for (int j = 0; j < JN; ++j)
                    acc[i][j] = fmaf(a[i], bv[j], acc[i][j]);
        }
        __syncthreads();
    }

    int b = m0 >> 11;
    if constexpr (MODE == 3) {
        float cmax[JN];
#pragma unroll
        for (int j = 0; j < JN; ++j) cmax[j] = -1e30f;
#pragma unroll
        for (int i = 0; i < 8; ++i)
#pragma unroll
            for (int j = 0; j < JN; ++j) {
                int o = o0 + tx * JN + j;
                float v = fmaf(acc[i][j], sc[o], sh[o]);
                v = (v >= 0.f) ? v : NEG * v;
                cmax[j] = fmaxf(cmax[j], v);
            }
        __syncthreads();
#pragma unroll
        for (int j = 0; j < JN; ++j) Bs[ty][tx * JN + j] = cmax[j];
        __syncthreads();
        if (ty == 0) {
#pragma unroll
            for (int j = 0; j < JN; ++j) {
                int o = o0 + tx * JN + j;
                float mval = -1e30f;
                for (int yy = 0; yy < 16; ++yy)
                    mval = fmaxf(mval, Bs[yy][tx * JN + j]);
                atomicMax(&gmax[b * 1024 + o], enc_f(mval));
            }
        }
        return;
    }

    bool fullstore = (o0 + TN <= O) && ((ldo & 3) == 0);
#pragma unroll
    for (int i = 0; i < 8; ++i) {
        int m = m0 + ty * 8 + i;
        float vals[JN];
#pragma unroll
        for (int j = 0; j < JN; ++j) {
            int o = o0 + tx * JN + j;
            float v = acc[i][j];
            if (MODE == 1) {
                if (addvec) v += addvec[b * O + o];
                v = fmaf(v, sc[o], sh[o]);
                v = (v >= 0.f) ? v : NEG * v;
            } else if (MODE == 2) {
                v += sh[o];
            }
            vals[j] = v;
        }
        if (fullstore) {
#pragma unroll
            for (int j0 = 0; j0 < JN; j0 += 4)
                *(float4*)&out[(size_t)m * ldo + o0 + tx * JN + j0] = *(float4*)&vals[j0];
        } else {
#pragma unroll
            for (int j = 0; j < JN; ++j) {
                int o = o0 + tx * JN + j;
                if (o < O) out[(size_t)m * ldo + o] = vals[j];
            }
        }
    }
}

// out[m][o..o+3] = max_k lrelu((y[nbr_k] + z[m]) * sc + sh); y/z packed in yz.
__global__ void edge_max_kernel(const float* __restrict__ yz, const int* __restrict__ idx,
                                const float* __restrict__ sc, const float* __restrict__ sh,
                                float* __restrict__ out, int ldo, int oshift) {
    int gid = blockIdx.x * 256 + threadIdx.x;
    int O = 1 << oshift;
    int m = gid >> (oshift - 2);
    int o = (gid & ((1 << (oshift - 2)) - 1)) << 2;
    int ldyz = 2 * O;
    float4 z = *(const float4*)&yz[(size_t)m * ldyz + O + o];
    float4 s4 = *(const float4*)&sc[o];
    float4 t4 = *(const float4*)&sh[o];
    const int* ip = idx + m * KNN;
    int bbase = m & ~(N_ - 1);
    float4 mv = make_float4(-1e30f, -1e30f, -1e30f, -1e30f);
#pragma unroll
    for (int kk = 0; kk < KNN; ++kk) {
        int j = ip[kk];
        float4 y = *(const float4*)&yz[(size_t)(bbase + j) * ldyz + o];
        float v;
        v = fmaf(y.x + z.x, s4.x, t4.x); v = (v >= 0.f) ? v : NEG * v; mv.x = fmaxf(mv.x, v);
        v = fmaf(y.y + z.y, s4.y, t4.y); v = (v >= 0.f) ? v : NEG * v; mv.y = fmaxf(mv.y, v);
        v = fmaf(y.z + z.z, s4.z, t4.z); v = (v >= 0.f) ? v : NEG * v; mv.z = fmaxf(mv.z, v);
        v = fmaf(y.w + z.w, s4.w, t4.w); v = (v >= 0.f) ? v : NEG * v; mv.w = fmaxf(mv.w, v);
    }
    *(float4*)&out[(size_t)m * ldo + o] = mv;
}

__global__ void init_gmax_kernel(unsigned* __restrict__ g) {
    int i = blockIdx.x * 256 + threadIdx.x;
    if (i < B_ * 1024) g[i] = enc_f(-1e30f);
}
__global__ void decode_gmax_kernel(const unsigned* __restrict__ g, float* __restrict__ glob) {
    int i = blockIdx.x * 256 + threadIdx.x;
    if (i < B_ * 1024) glob[i] = dec_f(g[i]);
}

// corr[b][o] = sum_c glob[b][c] * h1w[o][512+c]
__global__ void corr_kernel(const float* __restrict__ glob, const float* __restrict__ h1w,
                            float* __restrict__ corr) {
    int wid = (blockIdx.x * 256 + threadIdx.x) >> 6;
    int lane = threadIdx.x & 63;
    int b = wid >> 8, o = wid & 255;
    const float* g = glob + b * 1024;
    const float* w = h1w + (size_t)o * 1536 + 512;
    float s = 0.f;
    for (int c = lane; c < 1024; c += 64) s = fmaf(g[c], w[c], s);
#pragma unroll
    for (int off = 32; off >= 1; off >>= 1) s += __shfl_xor(s, off);
    if (lane == 0) corr[b * 256 + o] = s;
}

extern "C" void kernel_launch(void* const* d_in, const int* in_sizes, int n_in,
                              void* d_out, int out_size, void* d_ws, size_t ws_size,
                              hipStream_t stream) {
    const float* xyz    = (const float*)d_in[0];
    const float* ec1_w  = (const float*)d_in[1];
    const float* ec1_s  = (const float*)d_in[2];
    const float* ec1_t  = (const float*)d_in[3];
    const float* ec2_w  = (const float*)d_in[4];
    const float* ec2_s  = (const float*)d_in[5];
    const float* ec2_t  = (const float*)d_in[6];
    const float* ec3_w  = (const float*)d_in[7];
    const float* ec3_s  = (const float*)d_in[8];
    const float* ec3_t  = (const float*)d_in[9];
    const float* ec4_w  = (const float*)d_in[10];
    const float* ec4_s  = (const float*)d_in[11];
    const float* ec4_t  = (const float*)d_in[12];
    const float* fuse_w = (const float*)d_in[13];
    const float* fuse_s = (const float*)d_in[14];
    const float* fuse_t = (const float*)d_in[15];
    const float* emb_w  = (const float*)d_in[16];
    const float* emb_s  = (const float*)d_in[17];
    const float* emb_t  = (const float*)d_in[18];
    const float* h1_w   = (const float*)d_in[19];
    const float* h1_s   = (const float*)d_in[20];
    const float* h1_t   = (const float*)d_in[21];
    const float* h2_w   = (const float*)d_in[22];
    const float* h2_s   = (const float*)d_in[23];
    const float* h2_t   = (const float*)d_in[24];
    const float* h3_w   = (const float*)d_in[25];
    const float* h3_b   = (const float*)d_in[26];
    float* out = (float*)d_out;

    float* ws = (float*)d_ws;
    size_t off = 0;
    float* xcat = ws + off; off += (size_t)M_ * 512;
    float* xloc = ws + off; off += (size_t)M_ * 512;
    float* yz   = ws + off; off += (size_t)M_ * 512;
    float* xt   = ws + off; off += (size_t)B_ * 128 * N_;
    float* xx   = ws + off; off += M_;
    int*   idx  = (int*)(ws + off); off += (size_t)M_ * KNN;
    float* ws1  = ws + off; off += 2 * 64 * 16;
    float* ws2  = ws + off; off += 2 * 64 * 64;
    float* ws3  = ws + off; off += 2 * 128 * 64;
    float* ws4  = ws + off; off += 2 * 256 * 128;
    unsigned* gmax = (unsigned*)(ws + off); off += B_ * 1024;
    float* glob = ws + off; off += B_ * 1024;
    float* corr = ws + off; off += B_ * 256;
    float* h1o  = yz;
    float* h2o  = yz + (size_t)M_ * 256;

    wstack_kernel<<<(2 * 64 * 16 + 255) / 256, 256, 0, stream>>>(ec1_w, ws1, 64, 3, 16);
    wstack_kernel<<<(2 * 64 * 64 + 255) / 256, 256, 0, stream>>>(ec2_w, ws2, 64, 64, 64);
    wstack_kernel<<<(2 * 128 * 64 + 255) / 256, 256, 0, stream>>>(ec3_w, ws3, 128, 64, 64);
    wstack_kernel<<<(2 * 256 * 128 + 255) / 256, 256, 0, stream>>>(ec4_w, ws4, 256, 128, 128);

    // ---- EdgeConv 1: xyz (C=3) -> xcat[:, 0:64]
    prep_kernel<3><<<M_ / 256, 256, 0, stream>>>(xyz, 3, xx, xt);
    dist_topk_kernel<3><<<M_ / RM, 512, 0, stream>>>(xt, xx, idx);
    gemm_kernel<128, 0, false><<<dim3(1, M_ / 128), 256, 0, stream>>>(xyz, 3, ws1, 16, yz, 128, nullptr, nullptr, nullptr, nullptr, 3, 128);
    edge_max_kernel<<<(M_ * 16) / 256, 256, 0, stream>>>(yz, idx, ec1_s, ec1_t, xcat + 0, 512, 6);

    // ---- EdgeConv 2: x1 (C=64) -> xcat[:, 64:128]
    prep_kernel<64><<<M_ / 256, 256, 0, stream>>>(xcat + 0, 512, xx, xt);
    dist_topk_kernel<64><<<M_ / RM, 512, 0, stream>>>(xt, xx, idx);
    gemm_kernel<64, 0, true><<<dim3(2, M_ / 128), 256, 0, stream>>>(xcat + 0, 512, ws2, 64, yz, 128, nullptr, nullptr, nullptr, nullptr, 64, 128);
    edge_max_kernel<<<(M_ * 16) / 256, 256, 0, stream>>>(yz, idx, ec2_s, ec2_t, xcat + 64, 512, 6);

    // ---- EdgeConv 3: x2 (C=64) -> xcat[:, 128:256]
    prep_kernel<64><<<M_ / 256, 256, 0, stream>>>(xcat + 64, 512, xx, xt);
    dist_topk_kernel<64><<<M_ / RM, 512, 0, stream>>>(xt, xx, idx);
    gemm_kernel<128, 0, true><<<dim3(2, M_ / 128), 256, 0, stream>>>(xcat + 64, 512, ws3, 64, yz, 256, nullptr, nullptr, nullptr, nullptr, 64, 256);
    edge_max_kernel<<<(M_ * 32) / 256, 256, 0, stream>>>(yz, idx, ec3_s, ec3_t, xcat + 128, 512, 7);

    // ---- EdgeConv 4: x3 (C=128) -> xcat[:, 256:512]
    prep_kernel<128><<<M_ / 256, 256, 0, stream>>>(xcat + 128, 512, xx, xt);
    dist_topk_kernel<128><<<M_ / RM, 512, 0, stream>>>(xt, xx, idx);
    gemm_kernel<128, 0, true><<<dim3(4, M_ / 128), 256, 0, stream>>>(xcat + 128, 512, ws4, 128, yz, 512, nullptr, nullptr, nullptr, nullptr, 128, 512);
    edge_max_kernel<<<(M_ * 64) / 256, 256, 0, stream>>>(yz, idx, ec4_s, ec4_t, xcat + 256, 512, 8);

    // ---- fuse: xcat(512) -> x_local(512), lrelu
    gemm_kernel<128, 1, true><<<dim3(4, M_ / 128), 256, 0, stream>>>(xcat, 512, fuse_w, 512, xloc, 512, fuse_s, fuse_t, nullptr, nullptr, 512, 512);

    // ---- emb: x_local -> (max over N) glob, never materialized
    init_gmax_kernel<<<32, 256, 0, stream>>>(gmax);
    gemm_kernel<128, 3, true><<<dim3(8, M_ / 128), 256, 0, stream>>>(xloc, 512, emb_w, 512, nullptr, 0, emb_s, emb_t, nullptr, gmax, 512, 1024);
    decode_gmax_kernel<<<32, 256, 0, stream>>>(gmax, glob);
    corr_kernel<<<512, 256, 0, stream>>>(glob, h1_w, corr);

    // ---- h1: [x_local | glob] (1536) -> 256 ; glob part via corr
    gemm_kernel<128, 1, true><<<dim3(2, M_ / 128), 256, 0, stream>>>(xloc, 512, h1_w, 1536, h1o, 256, h1_s, h1_t, corr, nullptr, 512, 256);
    // ---- h2: 256 -> 256
    gemm_kernel<128, 1, true><<<dim3(2, M_ / 128), 256, 0, stream>>>(h1o, 256, h2_w, 256, h2o, 256, h2_s, h2_t, nullptr, nullptr, 256, 256);
    // ---- h3: 256 -> 13 (+bias)
    gemm_kernel<64, 2, true><<<dim3(1, M_ / 128), 256, 0, stream>>>(h2o, 256, h3_w, 256, out, 13, nullptr, h3_b, nullptr, nullptr, 256, 13);
}